// Round 7
// baseline (234.924 us; speedup 1.0000x reference)
//
#include <hip/hip_runtime.h>

// out[n,c,p,y,x] = in1[n,c,y,x] - zpad(in2)[n,c, y+i-3, x+j-3],  p = i*7+j
// N=8, C=32, H=W=112 -> out [8,32,49,112,112] fp32 (629 MB write, 25.7 MB read).
//
// R6: FILL-CLONE address pattern. R0-R5 established: nt stores hurt, LDS
// staging +4.5%, phase separation null, block-local store order null -- all
// structures stuck at ~129 us (5.1 TB/s) vs fill kernel 6.8 TB/s. Remaining
// difference: fill's grid-stride makes all ~2048 waves write ONE dense 4 MB
// lockstep-sweeping window (~16 DRAM rows/channel); our per-block private
// 2.4 MB regions give ~256 concurrent sweep points (row-buffer thrash).
// R6 = flat grid-stride over the output: e = tid + s*262144 f4 positions,
// decode (nc,p,y,x) per position, inputs read through hot L1/L2 (active
// input slice ~200 KB), window built with static-index selects (no scratch).

#define HW       112
#define PLANE    12544        // 112*112 floats
#define KK       49
#define NC_F4    153664       // 49*12544/4  f4 per nc
#define PLANE_F4 3136         // 12544/4
#define ROW_F4   28
#define TOTAL_F4 39337984     // 256*NC_F4
#define NTHREADS 262144       // 256 blocks * 1024 threads

typedef float f4 __attribute__((ext_vector_type(4)));

__global__ __launch_bounds__(1024) void sub2_flat(
    const float* __restrict__ in1,
    const float* __restrict__ in2,
    float* __restrict__ out)
{
    const int t0 = blockIdx.x * 1024 + threadIdx.x;   // 0..262143

    #pragma unroll 2
    for (int s = 0; s < 151; ++s) {
        const int e = t0 + s * NTHREADS;              // flat f4 index
        if (e < TOTAL_F4) {
            // ---- decode (nc, p, q, y, x0) ----
            const int nc = e / NC_F4;
            const int r  = e - nc * NC_F4;
            const int p  = r / PLANE_F4;
            const int q  = r - p * PLANE_F4;
            const int y  = q / ROW_F4;
            const int x4 = q - y * ROW_F4;
            const int x0 = x4 * 4;
            const int pi = p / 7;
            const int dy = pi - 3;
            const int dx = (p - pi * 7) - 3;

            const float* ip1 = in1 + (size_t)nc * PLANE;
            const float* ip2 = in2 + (size_t)nc * PLANE;

            // center f4 (coalesced 1KB/wave, L2-hot)
            const f4 a = *reinterpret_cast<const f4*>(ip1 + 4 * q);

            // ---- in2 window: 4 floats at row y+dy, cols x0+dx .. x0+dx+3 ----
            const int iy   = y + dy;
            const bool yok = ((unsigned)iy < (unsigned)HW);
            const int rowc = iy < 0 ? 0 : (iy > HW - 1 ? HW - 1 : iy);
            const int xb   = x0 + dx;                        // [-3, 114]
            const int B0   = x0 + (dx < 0 ? -4 : 0);         // aligned base
            const int B0c  = B0 < 0 ? 0 : B0;                // clamp left
            const int B1   = B0 + 4;
            const int B1c  = B1 > HW - 4 ? HW - 4 : B1;      // clamp right
            const float* rp = ip2 + rowc * HW;
            const f4 F0 = *reinterpret_cast<const f4*>(rp + B0c);
            const f4 F1 = *reinterpret_cast<const f4*>(rp + B1c);
            const int sh = (dx + 4) & 3;                     // shift 0..3

            // static-index selects (dynamic reg indexing would spill)
            const bool s0 = (sh == 0), s1 = (sh == 1), s2 = (sh == 2);
            float w0 = s0 ? F0.x : s1 ? F0.y : s2 ? F0.z : F0.w;
            float w1 = s0 ? F0.y : s1 ? F0.z : s2 ? F0.w : F1.x;
            float w2 = s0 ? F0.z : s1 ? F0.w : s2 ? F1.x : F1.y;
            float w3 = s0 ? F0.w : s1 ? F1.x : s2 ? F1.y : F1.z;

            // zero-mask out-of-range (covers clamped loads & padding)
            const bool v0 = yok && ((unsigned)(xb + 0) < (unsigned)HW);
            const bool v1 = yok && ((unsigned)(xb + 1) < (unsigned)HW);
            const bool v2 = yok && ((unsigned)(xb + 2) < (unsigned)HW);
            const bool v3 = yok && ((unsigned)(xb + 3) < (unsigned)HW);
            w0 = v0 ? w0 : 0.f;
            w1 = v1 ? w1 : 0.f;
            w2 = v2 ? w2 : 0.f;
            w3 = v3 ? w3 : 0.f;

            f4 res;
            res.x = a.x - w0;
            res.y = a.y - w1;
            res.z = a.z - w2;
            res.w = a.w - w3;
            *reinterpret_cast<f4*>(out + 4 * (size_t)e) = res;
        }
    }
}

extern "C" void kernel_launch(void* const* d_in, const int* in_sizes, int n_in,
                              void* d_out, int out_size, void* d_ws, size_t ws_size,
                              hipStream_t stream) {
    const float* in1 = (const float*)d_in[0];
    const float* in2 = (const float*)d_in[1];
    float* out = (float*)d_out;

    sub2_flat<<<256, 1024, 0, stream>>>(in1, in2, out);
}

// Round 8
// 124.784 us; speedup vs baseline: 1.8826x; 1.8826x over previous
//
#include <hip/hip_runtime.h>

// out[n,c,p,y,x] = in1[n,c,y,x] - zpad(in2)[n,c, y+i-3, x+j-3],  p = i*7+j
// N=8, C=32, H=W=112 -> out [8,32,49,112,112] fp32 (629 MB write, 25.7 MB read).
//
// R7 = R3 (best: 128.6 us) with ONE change: nontemporal stores.
// Re-analysis of history: R1(plane-block+nt)=172 vs R2(plane-block+plain)=249
// -> nt was +77us FASTER on that skeleton; R1's regression vs R0 was the
// plane-block structure, not nt. nt was never tested on the winning skeleton.
// Theory: 629 MB of write-allocate traffic churns the 4MB/XCD L2 (allocate +
// dirty-writeback + input eviction); nt streams past L2. All other levers
// (address order, phase separation, occupancy, store ILP) ablated null at
// ~129 us = 5.1 TB/s vs fill-calibrated 6.8 TB/s pure-write ceiling.

#define HW     112
#define PLANE  12544        // 112*112
#define KK     49
#define NC_TOT 256          // 8*32
#define YB     16           // output rows per block
#define LROWS  22           // YB + 6 halo rows
#define LDSW   132          // LDS row pitch: [0..7]=0pad, [8..119]=x, [120..131]=0pad

typedef float f4 __attribute__((ext_vector_type(4)));

__global__ __launch_bounds__(448) void sub2_kernel(
    const float* __restrict__ in1,
    const float* __restrict__ in2,
    float* __restrict__ out)
{
    __shared__ float smem[LROWS * LDSW];   // 11616 B

    const int b   = blockIdx.x;            // b = nc*7 + yb  (nc-major)
    const int nc  = b / 7;
    const int yb  = b - nc * 7;
    const int y0  = yb * YB;
    const int tid = threadIdx.x;

    // zero all of smem
    {
        const f4 z = {0.f, 0.f, 0.f, 0.f};
        for (int idx = tid; idx < (LROWS * LDSW) / 4; idx += 448)
            reinterpret_cast<f4*>(smem)[idx] = z;
    }
    __syncthreads();

    // stage in2 rows [y0-3, y0+18] into smem data region (28 f4 per row)
    const float* b_pl = in2 + (size_t)nc * PLANE;
    for (int idx = tid; idx < LROWS * 28; idx += 448) {
        const int r  = idx / 28;
        const int c  = idx - r * 28;
        const int gy = y0 - 3 + r;
        if (gy >= 0 && gy < HW) {
            *reinterpret_cast<f4*>(&smem[r * LDSW + 8 + 4 * c]) =
                *reinterpret_cast<const f4*>(b_pl + gy * HW + 4 * c);
        }
    }
    __syncthreads();

    const int yl = tid / 28;               // 0..15
    const int x0 = (tid - yl * 28) * 4;    // 0..108
    const int y  = y0 + yl;

    const f4 a = *reinterpret_cast<const f4*>(
        in1 + (size_t)nc * PLANE + y * HW + x0);
    float* o_base = out + (size_t)nc * KK * PLANE + (size_t)y * HW + x0;

    #pragma unroll
    for (int i = 0; i < 7; ++i) {
        // window floats x0-4 .. x0+11 (16B-aligned ds_read_b128 x4)
        const float* wr = &smem[(yl + i) * LDSW + 4 + x0];
        const f4 w0 = *reinterpret_cast<const f4*>(wr);
        const f4 w1 = *reinterpret_cast<const f4*>(wr + 4);
        const f4 w2 = *reinterpret_cast<const f4*>(wr + 8);
        const f4 w3 = *reinterpret_cast<const f4*>(wr + 12);
        float wf[16];
        wf[0]=w0.x;  wf[1]=w0.y;  wf[2]=w0.z;  wf[3]=w0.w;
        wf[4]=w1.x;  wf[5]=w1.y;  wf[6]=w1.z;  wf[7]=w1.w;
        wf[8]=w2.x;  wf[9]=w2.y;  wf[10]=w2.z; wf[11]=w2.w;
        wf[12]=w3.x; wf[13]=w3.y; wf[14]=w3.z; wf[15]=w3.w;

        #pragma unroll
        for (int j = 0; j < 7; ++j) {
            f4 r;
            r.x = a.x - wf[j + 1];
            r.y = a.y - wf[j + 2];
            r.z = a.z - wf[j + 3];
            r.w = a.w - wf[j + 4];
            __builtin_nontemporal_store(
                r, reinterpret_cast<f4*>(o_base + (size_t)(i * 7 + j) * PLANE));
        }
    }
}

extern "C" void kernel_launch(void* const* d_in, const int* in_sizes, int n_in,
                              void* d_out, int out_size, void* d_ws, size_t ws_size,
                              hipStream_t stream) {
    const float* in1 = (const float*)d_in[0];
    const float* in2 = (const float*)d_in[1];
    float* out = (float*)d_out;

    const int blocks = NC_TOT * 7;   // 1792, b = nc*7 + yb
    sub2_kernel<<<blocks, 448, 0, stream>>>(in1, in2, out);
}